// Round 4
// baseline (382.209 us; speedup 1.0000x reference)
//
#include <hip/hip_runtime.h>
#include <stdint.h>

typedef __attribute__((ext_vector_type(8))) unsigned short ushort8;
typedef __attribute__((ext_vector_type(8))) __bf16 bf16x8;
typedef __attribute__((ext_vector_type(4))) float f32x4;

#define TBK 32

__device__ __forceinline__ unsigned short f2bf(float f) {
  union { float f; uint32_t u; } x; x.f = f;
  uint32_t u = x.u;
  uint32_t r = (u + 0x7fffu + ((u >> 16) & 1u)) >> 16;
  return (unsigned short)r;
}

__device__ __forceinline__ void store_c(unsigned short* p, float v) { *p = f2bf(v); }
__device__ __forceinline__ void store_c(float* p, float v) { *p = v; }

__device__ __forceinline__ void gll16(const unsigned short* g, unsigned short* l) {
  __builtin_amdgcn_global_load_lds((const __attribute__((address_space(1))) void*)g,
                                   (__attribute__((address_space(3))) void*)l,
                                   16, 0, 0);
}

// ---------------------------------------------------------------------------
// fp32 -> bf16 convert (RNE). One thread = 4 elements.
// ---------------------------------------------------------------------------
__global__ __launch_bounds__(256) void cvt_f32_bf16(
    const float* __restrict__ x, unsigned short* __restrict__ y, int n4) {
  int i = blockIdx.x * 256 + threadIdx.x;
  if (i >= n4) return;
  float4 v = *(const float4*)(x + (size_t)i * 4);
  uint32_t lo = (uint32_t)f2bf(v.x) | ((uint32_t)f2bf(v.y) << 16);
  uint32_t hi = (uint32_t)f2bf(v.z) | ((uint32_t)f2bf(v.w) << 16);
  uint2 p; p.x = lo; p.y = hi;
  *(uint2*)(y + (size_t)i * 4) = p;
}

// ---------------------------------------------------------------------------
// Weight transpose + convert: WT[n][k] = bf16(W[k][n]), 1024x1024 fp32 in.
// block (32,8), grid (32,32).
// ---------------------------------------------------------------------------
__global__ void transpose_w(const float* __restrict__ W,
                            unsigned short* __restrict__ WT) {
  __shared__ unsigned short tile[32][33];
  int c0 = blockIdx.x * 32, r0 = blockIdx.y * 32;
  int x = threadIdx.x, y = threadIdx.y;
#pragma unroll
  for (int i = 0; i < 32; i += 8)
    tile[y + i][x] = f2bf(W[(size_t)(r0 + y + i) * 1024 + c0 + x]);
  __syncthreads();
#pragma unroll
  for (int i = 0; i < 32; i += 8)
    WT[(size_t)(c0 + y + i) * 1024 + r0 + x] = tile[x][y + i];
}

// ---------------------------------------------------------------------------
// GEMM: C[M,N] = A[M,K]*B[K,N] given BT[N,K], bf16 in, fp32 accum.
// Output type templated: bf16 (intermediate) or fp32 (final d_out).
// m97 structure: 128x128 tile, 4 waves each 64x64, BK=32, global_load_lds.
// grid (M/128, N/128, nz); z selects BT/C.
// ---------------------------------------------------------------------------
template <typename OutT>
__global__ __launch_bounds__(256) void gemm_bt(
    const unsigned short* A,
    const unsigned short* BT0, const unsigned short* BT1, const unsigned short* BT2,
    OutT* C0, OutT* C1, OutT* C2,
    int M, int N, int K) {
  const unsigned short* BT = (blockIdx.z == 0) ? BT0 : (blockIdx.z == 1) ? BT1 : BT2;
  OutT* C = (blockIdx.z == 0) ? C0 : (blockIdx.z == 1) ? C1 : C2;

  __shared__ __attribute__((aligned(16))) unsigned short As[128 * TBK];
  __shared__ __attribute__((aligned(16))) unsigned short Bs[128 * TBK];

  const int tid = threadIdx.x;
  const int wave = tid >> 6, lane = tid & 63;
  const int fr = lane & 15, fq = lane >> 4;
  const int bm = blockIdx.x * 128, bn = blockIdx.y * 128;
  const int wm = (wave >> 1) * 64, wn = (wave & 1) * 64;

  f32x4 acc[4][4] = {};

  const int sr = lane >> 2;
  const int sk = (lane & 3) * 8;
  const unsigned short* Ag = A + (size_t)(bm + wave * 32 + sr) * K + sk;
  const unsigned short* Bg = BT + (size_t)(bn + wave * 32 + sr) * K + sk;
  unsigned short* As0 = &As[(wave * 32) * TBK];
  unsigned short* Bs0 = &Bs[(wave * 32) * TBK];

  for (int k0 = 0; k0 < K; k0 += TBK) {
    gll16(Ag + k0, As0);
    gll16(Ag + k0 + 16 * K, As0 + 16 * TBK);
    gll16(Bg + k0, Bs0);
    gll16(Bg + k0 + 16 * K, Bs0 + 16 * TBK);
    asm volatile("s_waitcnt vmcnt(0)" ::: "memory");
    __syncthreads();

    bf16x8 af[4], bfr[4];
#pragma unroll
    for (int mt = 0; mt < 4; mt++)
      af[mt] = *(const bf16x8*)&As[(wm + mt * 16 + fr) * TBK + fq * 8];
#pragma unroll
    for (int nt = 0; nt < 4; nt++)
      bfr[nt] = *(const bf16x8*)&Bs[(wn + nt * 16 + fr) * TBK + fq * 8];
#pragma unroll
    for (int mt = 0; mt < 4; mt++)
#pragma unroll
      for (int nt = 0; nt < 4; nt++)
        acc[mt][nt] = __builtin_amdgcn_mfma_f32_16x16x32_bf16(af[mt], bfr[nt], acc[mt][nt], 0, 0, 0);
    __syncthreads();
  }

#pragma unroll
  for (int mt = 0; mt < 4; mt++)
#pragma unroll
    for (int nt = 0; nt < 4; nt++)
#pragma unroll
      for (int r = 0; r < 4; r++) {
        int row = bm + wm + mt * 16 + fq * 4 + r;
        int col = bn + wn + nt * 16 + fr;
        store_c(&C[(size_t)row * N + col], acc[mt][nt][r]);
      }
}

// ---------------------------------------------------------------------------
// Flash attention (no-max softmax: scores bounded, fp32 exp safe; softmax is
// shift-invariant). One block = 64 query rows of one (b,h). 4 waves x 16
// rows. K/V tiles of 64. Layout [B*S, H*64]. o aliases q (disjoint blocks).
// ---------------------------------------------------------------------------
#define SQ 72  // LDS row stride: 16B-aligned, breaks pow2 banks

__global__ __launch_bounds__(256) void attn_kernel(
    const unsigned short* q, const unsigned short* k,
    const unsigned short* v, unsigned short* o) {
  const int S = 2048, E = 1024;
  __shared__ __attribute__((aligned(16))) unsigned short Qs[64 * SQ];
  __shared__ __attribute__((aligned(16))) unsigned short Ks[64 * SQ];
  __shared__ __attribute__((aligned(16))) unsigned short Vt[64 * SQ];  // [d][t]
  __shared__ __attribute__((aligned(16))) unsigned short Ps[4][16 * SQ];

  const int tid = threadIdx.x;
  const int wave = tid >> 6, lane = tid & 63;
  const int fr = lane & 15, fq = lane >> 4;
  const int q0 = blockIdx.x * 64;
  const int bh = blockIdx.y;
  const int b = bh >> 4, h = bh & 15;
  const size_t base = ((size_t)b * S) * E + (size_t)h * 64;

#pragma unroll
  for (int i = 0; i < 2; i++) {
    int id = tid + i * 256;
    int row = id >> 3, dc = (id & 7) * 8;
    ushort8 val = *(const ushort8*)&q[base + (size_t)(q0 + row) * E + dc];
    *(ushort8*)&Qs[row * SQ + dc] = val;
  }

  f32x4 oacc[4] = {};
  float lsum[4] = {0.f, 0.f, 0.f, 0.f};
  const float KSC = 0.125f * 1.44269504088896341f;  // head_scale * log2(e)

  const int rp = (tid & 31) * 2;
  const int dcv = (tid >> 5) * 8;

  for (int t0 = 0; t0 < S; t0 += 64) {
    __syncthreads();
#pragma unroll
    for (int i = 0; i < 2; i++) {
      int id = tid + i * 256;
      int row = id >> 3, dc = (id & 7) * 8;
      ushort8 kv = *(const ushort8*)&k[base + (size_t)(t0 + row) * E + dc];
      *(ushort8*)&Ks[row * SQ + dc] = kv;
    }
    {
      ushort8 v0 = *(const ushort8*)&v[base + (size_t)(t0 + rp) * E + dcv];
      ushort8 v1 = *(const ushort8*)&v[base + (size_t)(t0 + rp + 1) * E + dcv];
#pragma unroll
      for (int j = 0; j < 8; j++) {
        uint32_t w = (uint32_t)v0[j] | ((uint32_t)v1[j] << 16);
        *(uint32_t*)&Vt[(dcv + j) * SQ + rp] = w;
      }
    }
    __syncthreads();

    f32x4 sc[4] = {};
#pragma unroll
    for (int ks = 0; ks < 2; ks++) {
      bf16x8 aq = *(const bf16x8*)&Qs[(wave * 16 + fr) * SQ + ks * 32 + fq * 8];
#pragma unroll
      for (int nt = 0; nt < 4; nt++) {
        bf16x8 bk = *(const bf16x8*)&Ks[(nt * 16 + fr) * SQ + ks * 32 + fq * 8];
        sc[nt] = __builtin_amdgcn_mfma_f32_16x16x32_bf16(aq, bk, sc[nt], 0, 0, 0);
      }
    }

    float p[4][4];
#pragma unroll
    for (int nt = 0; nt < 4; nt++)
#pragma unroll
      for (int r = 0; r < 4; r++)
        p[nt][r] = __builtin_amdgcn_exp2f(sc[nt][r] * KSC);
#pragma unroll
    for (int r = 0; r < 4; r++) {
      float s = p[0][r] + p[1][r] + p[2][r] + p[3][r];
      s += __shfl_xor(s, 1);
      s += __shfl_xor(s, 2);
      s += __shfl_xor(s, 4);
      s += __shfl_xor(s, 8);
      lsum[r] += s;
    }

    unsigned short* Pw = &Ps[wave][0];
#pragma unroll
    for (int nt = 0; nt < 4; nt++)
#pragma unroll
      for (int r = 0; r < 4; r++)
        Pw[(fq * 4 + r) * SQ + nt * 16 + fr] = f2bf(p[nt][r]);
    __threadfence_block();

#pragma unroll
    for (int ks = 0; ks < 2; ks++) {
      bf16x8 ap = *(const bf16x8*)&Pw[fr * SQ + ks * 32 + fq * 8];
#pragma unroll
      for (int dt = 0; dt < 4; dt++) {
        bf16x8 bv = *(const bf16x8*)&Vt[(dt * 16 + fr) * SQ + ks * 32 + fq * 8];
        oacc[dt] = __builtin_amdgcn_mfma_f32_16x16x32_bf16(ap, bv, oacc[dt], 0, 0, 0);
      }
    }
  }

#pragma unroll
  for (int r = 0; r < 4; r++) {
    float inv = 1.0f / lsum[r];
    int row = q0 + wave * 16 + fq * 4 + r;
#pragma unroll
    for (int dt = 0; dt < 4; dt++)
      o[base + (size_t)row * E + dt * 16 + fr] = f2bf(oacc[dt][r] * inv);
  }
}

// ---------------------------------------------------------------------------
// ws: 3 x 1M (weights) + 3 x 8M (q/k/v) shorts = 54 MB.
// bf16 hidden_states lives in d_out's first 16 MB (d_out is 33.5 MB fp32;
// dead before the final GEMM overwrites all of it).
// woT reuses wqT's slot (transposed after the QKV GEMM).
// Final GEMM writes fp32 directly to d_out (reference output dtype = fp32).
// ---------------------------------------------------------------------------
extern "C" void kernel_launch(void* const* d_in, const int* in_sizes, int n_in,
                              void* d_out, int out_size, void* d_ws, size_t ws_size,
                              hipStream_t stream) {
  const float* hs = (const float*)d_in[0];
  const float* wq = (const float*)d_in[1];
  const float* wk = (const float*)d_in[2];
  const float* wv = (const float*)d_in[3];
  const float* wo = (const float*)d_in[4];
  unsigned short* ws = (unsigned short*)d_ws;

  unsigned short* wqT = ws;                    // 1M shorts each
  unsigned short* wkT = ws + 1048576;
  unsigned short* wvT = ws + 2097152;
  unsigned short* woT = wqT;                   // reuses wqT after QKV GEMM
  unsigned short* qb  = ws + 3145728;          // 8M shorts each
  unsigned short* kb  = qb + 8388608;
  unsigned short* vb  = kb + 8388608;
  unsigned short* ob  = qb;                    // attn output aliases q (safe)
  unsigned short* hsb = (unsigned short*)d_out;  // 16 MB scratch phase
  float* out = (float*)d_out;                  // fp32 final output

  const int M = 8192, N = 1024, K = 1024;

  cvt_f32_bf16<<<dim3(M * K / 4 / 256), 256, 0, stream>>>(hs, hsb, M * K / 4);

  dim3 tb(32, 8);
  transpose_w<<<dim3(32, 32), tb, 0, stream>>>(wq, wqT);
  transpose_w<<<dim3(32, 32), tb, 0, stream>>>(wk, wkT);
  transpose_w<<<dim3(32, 32), tb, 0, stream>>>(wv, wvT);

  gemm_bt<unsigned short><<<dim3(M / 128, N / 128, 3), 256, 0, stream>>>(
      hsb, wqT, wkT, wvT, qb, kb, vb, M, N, K);

  transpose_w<<<dim3(32, 32), tb, 0, stream>>>(wo, woT);

  attn_kernel<<<dim3(2048 / 64, 64), 256, 0, stream>>>(qb, kb, vb, ob);

  gemm_bt<float><<<dim3(M / 128, N / 128, 1), 256, 0, stream>>>(
      ob, woT, woT, woT, out, out, out, M, N, K);
}

// Round 5
// 346.514 us; speedup vs baseline: 1.1030x; 1.1030x over previous
//
#include <hip/hip_runtime.h>
#include <stdint.h>

typedef __attribute__((ext_vector_type(8))) unsigned short ushort8;
typedef __attribute__((ext_vector_type(8))) __bf16 bf16x8;
typedef __attribute__((ext_vector_type(4))) float f32x4;

#define TBK 32

__device__ __forceinline__ unsigned short f2bf(float f) {
  union { float f; uint32_t u; } x; x.f = f;
  uint32_t u = x.u;
  uint32_t r = (u + 0x7fffu + ((u >> 16) & 1u)) >> 16;
  return (unsigned short)r;
}

__device__ __forceinline__ void store_c(unsigned short* p, float v) { *p = f2bf(v); }
__device__ __forceinline__ void store_c(float* p, float v) { *p = v; }

__device__ __forceinline__ void gll16(const unsigned short* g, unsigned short* l) {
  __builtin_amdgcn_global_load_lds((const __attribute__((address_space(1))) void*)g,
                                   (__attribute__((address_space(3))) void*)l,
                                   16, 0, 0);
}

// ---------------------------------------------------------------------------
// fp32 -> bf16 convert (RNE). One thread = 4 elements.
// ---------------------------------------------------------------------------
__global__ __launch_bounds__(256) void cvt_f32_bf16(
    const float* __restrict__ x, unsigned short* __restrict__ y, int n4) {
  int i = blockIdx.x * 256 + threadIdx.x;
  if (i >= n4) return;
  float4 v = *(const float4*)(x + (size_t)i * 4);
  uint32_t lo = (uint32_t)f2bf(v.x) | ((uint32_t)f2bf(v.y) << 16);
  uint32_t hi = (uint32_t)f2bf(v.z) | ((uint32_t)f2bf(v.w) << 16);
  uint2 p; p.x = lo; p.y = hi;
  *(uint2*)(y + (size_t)i * 4) = p;
}

// ---------------------------------------------------------------------------
// Weight transpose + convert: WT[n][k] = bf16(W[k][n]), 1024x1024 fp32 in.
// ---------------------------------------------------------------------------
__global__ void transpose_w(const float* __restrict__ W,
                            unsigned short* __restrict__ WT) {
  __shared__ unsigned short tile[32][33];
  int c0 = blockIdx.x * 32, r0 = blockIdx.y * 32;
  int x = threadIdx.x, y = threadIdx.y;
#pragma unroll
  for (int i = 0; i < 32; i += 8)
    tile[y + i][x] = f2bf(W[(size_t)(r0 + y + i) * 1024 + c0 + x]);
  __syncthreads();
#pragma unroll
  for (int i = 0; i < 32; i += 8)
    WT[(size_t)(c0 + y + i) * 1024 + r0 + x] = tile[x][y + i];
}

// ---------------------------------------------------------------------------
// GEMM: C[M,N] = A[M,K]*B[K,N] given BT[N,K], bf16 in, fp32 accum.
// m97 structure: 128x128 tile, 4 waves each 64x64, BK=32, global_load_lds.
// ---------------------------------------------------------------------------
template <typename OutT>
__global__ __launch_bounds__(256) void gemm_bt(
    const unsigned short* A,
    const unsigned short* BT0, const unsigned short* BT1, const unsigned short* BT2,
    OutT* C0, OutT* C1, OutT* C2,
    int M, int N, int K) {
  const unsigned short* BT = (blockIdx.z == 0) ? BT0 : (blockIdx.z == 1) ? BT1 : BT2;
  OutT* C = (blockIdx.z == 0) ? C0 : (blockIdx.z == 1) ? C1 : C2;

  __shared__ __attribute__((aligned(16))) unsigned short As[128 * TBK];
  __shared__ __attribute__((aligned(16))) unsigned short Bs[128 * TBK];

  const int tid = threadIdx.x;
  const int wave = tid >> 6, lane = tid & 63;
  const int fr = lane & 15, fq = lane >> 4;
  const int bm = blockIdx.x * 128, bn = blockIdx.y * 128;
  const int wm = (wave >> 1) * 64, wn = (wave & 1) * 64;

  f32x4 acc[4][4] = {};

  const int sr = lane >> 2;
  const int sk = (lane & 3) * 8;
  const unsigned short* Ag = A + (size_t)(bm + wave * 32 + sr) * K + sk;
  const unsigned short* Bg = BT + (size_t)(bn + wave * 32 + sr) * K + sk;
  unsigned short* As0 = &As[(wave * 32) * TBK];
  unsigned short* Bs0 = &Bs[(wave * 32) * TBK];

  for (int k0 = 0; k0 < K; k0 += TBK) {
    gll16(Ag + k0, As0);
    gll16(Ag + k0 + 16 * K, As0 + 16 * TBK);
    gll16(Bg + k0, Bs0);
    gll16(Bg + k0 + 16 * K, Bs0 + 16 * TBK);
    asm volatile("s_waitcnt vmcnt(0)" ::: "memory");
    __syncthreads();

    bf16x8 af[4], bfr[4];
#pragma unroll
    for (int mt = 0; mt < 4; mt++)
      af[mt] = *(const bf16x8*)&As[(wm + mt * 16 + fr) * TBK + fq * 8];
#pragma unroll
    for (int nt = 0; nt < 4; nt++)
      bfr[nt] = *(const bf16x8*)&Bs[(wn + nt * 16 + fr) * TBK + fq * 8];
#pragma unroll
    for (int mt = 0; mt < 4; mt++)
#pragma unroll
      for (int nt = 0; nt < 4; nt++)
        acc[mt][nt] = __builtin_amdgcn_mfma_f32_16x16x32_bf16(af[mt], bfr[nt], acc[mt][nt], 0, 0, 0);
    __syncthreads();
  }

#pragma unroll
  for (int mt = 0; mt < 4; mt++)
#pragma unroll
    for (int nt = 0; nt < 4; nt++)
#pragma unroll
      for (int r = 0; r < 4; r++) {
        int row = bm + wm + mt * 16 + fq * 4 + r;
        int col = bn + wn + nt * 16 + fr;
        store_c(&C[(size_t)row * N + col], acc[mt][nt][r]);
      }
}

// ---------------------------------------------------------------------------
// Flash attention. One block = 64 q-rows of one (b,h); 4 waves x 16 rows.
// No-max softmax (scores bounded; softmax shift-invariant).
// R5: Q fragments hoisted out of t-loop; row-sums via ones-column MFMA
// (extra B-fragment of 1.0 -> lsum lands in an accumulator; no shuffles).
// ---------------------------------------------------------------------------
#define SQ 72  // LDS row stride: 16B-aligned, breaks pow2 banks

__global__ __launch_bounds__(256) void attn_kernel(
    const unsigned short* q, const unsigned short* k,
    const unsigned short* v, unsigned short* o) {
  const int S = 2048, E = 1024;
  __shared__ __attribute__((aligned(16))) unsigned short Qs[64 * SQ];
  __shared__ __attribute__((aligned(16))) unsigned short Ks[64 * SQ];
  __shared__ __attribute__((aligned(16))) unsigned short Vt[64 * SQ];  // [d][t]
  __shared__ __attribute__((aligned(16))) unsigned short Ps[4][16 * SQ];

  const int tid = threadIdx.x;
  const int wave = tid >> 6, lane = tid & 63;
  const int fr = lane & 15, fq = lane >> 4;
  const int q0 = blockIdx.x * 64;
  const int bh = blockIdx.y;
  const int b = bh >> 4, h = bh & 15;
  const size_t base = ((size_t)b * S) * E + (size_t)h * 64;

#pragma unroll
  for (int i = 0; i < 2; i++) {
    int id = tid + i * 256;
    int row = id >> 3, dc = (id & 7) * 8;
    ushort8 val = *(const ushort8*)&q[base + (size_t)(q0 + row) * E + dc];
    *(ushort8*)&Qs[row * SQ + dc] = val;
  }
  __syncthreads();

  // hoisted Q fragments (invariant over t-loop)
  bf16x8 aq[2];
#pragma unroll
  for (int ks = 0; ks < 2; ks++)
    aq[ks] = *(const bf16x8*)&Qs[(wave * 16 + fr) * SQ + ks * 32 + fq * 8];

  // constant ones B-fragment for the row-sum MFMA
  ushort8 ones_u;
#pragma unroll
  for (int j = 0; j < 8; j++) ones_u[j] = 0x3F80;  // bf16 1.0
  bf16x8 onesf = *(bf16x8*)&ones_u;

  f32x4 oacc[4] = {};
  f32x4 osum = {};
  const float KSC = 0.125f * 1.44269504088896341f;  // head_scale * log2(e)

  const int rp = (tid & 31) * 2;
  const int dcv = (tid >> 5) * 8;

  for (int t0 = 0; t0 < S; t0 += 64) {
    __syncthreads();
#pragma unroll
    for (int i = 0; i < 2; i++) {
      int id = tid + i * 256;
      int row = id >> 3, dc = (id & 7) * 8;
      ushort8 kv = *(const ushort8*)&k[base + (size_t)(t0 + row) * E + dc];
      *(ushort8*)&Ks[row * SQ + dc] = kv;
    }
    {
      ushort8 v0 = *(const ushort8*)&v[base + (size_t)(t0 + rp) * E + dcv];
      ushort8 v1 = *(const ushort8*)&v[base + (size_t)(t0 + rp + 1) * E + dcv];
#pragma unroll
      for (int j = 0; j < 8; j++) {
        uint32_t w = (uint32_t)v0[j] | ((uint32_t)v1[j] << 16);
        *(uint32_t*)&Vt[(dcv + j) * SQ + rp] = w;
      }
    }
    __syncthreads();

    // S = Q * K^T  (wave's 16 rows x 64 cols)
    f32x4 sc[4] = {};
#pragma unroll
    for (int ks = 0; ks < 2; ks++) {
#pragma unroll
      for (int nt = 0; nt < 4; nt++) {
        bf16x8 bk = *(const bf16x8*)&Ks[(nt * 16 + fr) * SQ + ks * 32 + fq * 8];
        sc[nt] = __builtin_amdgcn_mfma_f32_16x16x32_bf16(aq[ks], bk, sc[nt], 0, 0, 0);
      }
    }

    // p = exp2(s * scale * log2e); write to LDS in A-operand layout
    unsigned short* Pw = &Ps[wave][0];
#pragma unroll
    for (int nt = 0; nt < 4; nt++)
#pragma unroll
      for (int r = 0; r < 4; r++)
        Pw[(fq * 4 + r) * SQ + nt * 16 + fr] =
            f2bf(__builtin_amdgcn_exp2f(sc[nt][r] * KSC));
    __threadfence_block();

    // O += P * V ; osum += P * 1 (row sums via ones-column MFMA)
#pragma unroll
    for (int ks = 0; ks < 2; ks++) {
      bf16x8 ap = *(const bf16x8*)&Pw[fr * SQ + ks * 32 + fq * 8];
#pragma unroll
      for (int dt = 0; dt < 4; dt++) {
        bf16x8 bv = *(const bf16x8*)&Vt[(dt * 16 + fr) * SQ + ks * 32 + fq * 8];
        oacc[dt] = __builtin_amdgcn_mfma_f32_16x16x32_bf16(ap, bv, oacc[dt], 0, 0, 0);
      }
      osum = __builtin_amdgcn_mfma_f32_16x16x32_bf16(ap, onesf, osum, 0, 0, 0);
    }
  }

#pragma unroll
  for (int r = 0; r < 4; r++) {
    float inv = 1.0f / osum[r];
    int row = q0 + wave * 16 + fq * 4 + r;
#pragma unroll
    for (int dt = 0; dt < 4; dt++)
      o[base + (size_t)row * E + dt * 16 + fr] = f2bf(oacc[dt][r] * inv);
  }
}

// ---------------------------------------------------------------------------
// ws: 3 x 1M (weights) + 3 x 8M (q/k/v) shorts = 54 MB.
// bf16 hidden_states lives in d_out's first 16 MB (dead before final GEMM).
// woT reuses wqT's slot. Final GEMM writes fp32 to d_out.
// ---------------------------------------------------------------------------
extern "C" void kernel_launch(void* const* d_in, const int* in_sizes, int n_in,
                              void* d_out, int out_size, void* d_ws, size_t ws_size,
                              hipStream_t stream) {
  const float* hs = (const float*)d_in[0];
  const float* wq = (const float*)d_in[1];
  const float* wk = (const float*)d_in[2];
  const float* wv = (const float*)d_in[3];
  const float* wo = (const float*)d_in[4];
  unsigned short* ws = (unsigned short*)d_ws;

  unsigned short* wqT = ws;
  unsigned short* wkT = ws + 1048576;
  unsigned short* wvT = ws + 2097152;
  unsigned short* woT = wqT;
  unsigned short* qb  = ws + 3145728;
  unsigned short* kb  = qb + 8388608;
  unsigned short* vb  = kb + 8388608;
  unsigned short* ob  = qb;
  unsigned short* hsb = (unsigned short*)d_out;
  float* out = (float*)d_out;

  const int M = 8192, N = 1024, K = 1024;

  cvt_f32_bf16<<<dim3(M * K / 4 / 256), 256, 0, stream>>>(hs, hsb, M * K / 4);

  dim3 tb(32, 8);
  transpose_w<<<dim3(32, 32), tb, 0, stream>>>(wq, wqT);
  transpose_w<<<dim3(32, 32), tb, 0, stream>>>(wk, wkT);
  transpose_w<<<dim3(32, 32), tb, 0, stream>>>(wv, wvT);

  gemm_bt<unsigned short><<<dim3(M / 128, N / 128, 3), 256, 0, stream>>>(
      hsb, wqT, wkT, wvT, qb, kb, vb, M, N, K);

  transpose_w<<<dim3(32, 32), tb, 0, stream>>>(wo, woT);

  attn_kernel<<<dim3(2048 / 64, 64), 256, 0, stream>>>(qb, kb, vb, ob);

  gemm_bt<float><<<dim3(M / 128, N / 128, 1), 256, 0, stream>>>(
      ob, woT, woT, woT, out, out, out, M, N, K);
}

// Round 7
// 323.094 us; speedup vs baseline: 1.1830x; 1.0725x over previous
//
#include <hip/hip_runtime.h>
#include <stdint.h>

typedef __attribute__((ext_vector_type(8))) unsigned short ushort8;
typedef __attribute__((ext_vector_type(8))) __bf16 bf16x8;
typedef __attribute__((ext_vector_type(4))) float f32x4;
typedef __attribute__((ext_vector_type(4))) uint32_t u32x4;

#define TBK 32

__device__ __forceinline__ unsigned short f2bf(float f) {
  union { float f; uint32_t u; } x; x.f = f;
  uint32_t u = x.u;
  uint32_t r = (u + 0x7fffu + ((u >> 16) & 1u)) >> 16;
  return (unsigned short)r;
}

__device__ __forceinline__ uint32_t pack_bf2(float lo, float hi) {
  return (uint32_t)f2bf(lo) | ((uint32_t)f2bf(hi) << 16);
}

__device__ __forceinline__ void store_c(unsigned short* p, float v) { *p = f2bf(v); }
__device__ __forceinline__ void store_c(float* p, float v) { *p = v; }

__device__ __forceinline__ void gll16(const unsigned short* g, unsigned short* l) {
  __builtin_amdgcn_global_load_lds((const __attribute__((address_space(1))) void*)g,
                                   (__attribute__((address_space(3))) void*)l,
                                   16, 0, 0);
}

// ---------------------------------------------------------------------------
// fp32 -> bf16 convert (RNE). One thread = 4 elements.
// ---------------------------------------------------------------------------
__global__ __launch_bounds__(256) void cvt_f32_bf16(
    const float* __restrict__ x, unsigned short* __restrict__ y, int n4) {
  int i = blockIdx.x * 256 + threadIdx.x;
  if (i >= n4) return;
  float4 v = *(const float4*)(x + (size_t)i * 4);
  uint2 p; p.x = pack_bf2(v.x, v.y); p.y = pack_bf2(v.z, v.w);
  *(uint2*)(y + (size_t)i * 4) = p;
}

// ---------------------------------------------------------------------------
// Weight transpose + convert: WT[n][k] = bf16(W[k][n]), 1024x1024 fp32 in.
// ---------------------------------------------------------------------------
__global__ void transpose_w(const float* __restrict__ W,
                            unsigned short* __restrict__ WT) {
  __shared__ unsigned short tile[32][33];
  int c0 = blockIdx.x * 32, r0 = blockIdx.y * 32;
  int x = threadIdx.x, y = threadIdx.y;
#pragma unroll
  for (int i = 0; i < 32; i += 8)
    tile[y + i][x] = f2bf(W[(size_t)(r0 + y + i) * 1024 + c0 + x]);
  __syncthreads();
#pragma unroll
  for (int i = 0; i < 32; i += 8)
    WT[(size_t)(c0 + y + i) * 1024 + r0 + x] = tile[x][y + i];
}

// ---------------------------------------------------------------------------
// GEMM: C[M,N] = A[M,K]*B[K,N] given BT[N,K], bf16 in, fp32 accum.
// m97 structure: 128x128 tile, 4 waves each 64x64, BK=32, global_load_lds.
// ---------------------------------------------------------------------------
template <typename OutT>
__global__ __launch_bounds__(256) void gemm_bt(
    const unsigned short* A,
    const unsigned short* BT0, const unsigned short* BT1, const unsigned short* BT2,
    OutT* C0, OutT* C1, OutT* C2,
    int M, int N, int K) {
  const unsigned short* BT = (blockIdx.z == 0) ? BT0 : (blockIdx.z == 1) ? BT1 : BT2;
  OutT* C = (blockIdx.z == 0) ? C0 : (blockIdx.z == 1) ? C1 : C2;

  __shared__ __attribute__((aligned(16))) unsigned short As[128 * TBK];
  __shared__ __attribute__((aligned(16))) unsigned short Bs[128 * TBK];

  const int tid = threadIdx.x;
  const int wave = tid >> 6, lane = tid & 63;
  const int fr = lane & 15, fq = lane >> 4;
  const int bm = blockIdx.x * 128, bn = blockIdx.y * 128;
  const int wm = (wave >> 1) * 64, wn = (wave & 1) * 64;

  f32x4 acc[4][4] = {};

  const int sr = lane >> 2;
  const int sk = (lane & 3) * 8;
  const unsigned short* Ag = A + (size_t)(bm + wave * 32 + sr) * K + sk;
  const unsigned short* Bg = BT + (size_t)(bn + wave * 32 + sr) * K + sk;
  unsigned short* As0 = &As[(wave * 32) * TBK];
  unsigned short* Bs0 = &Bs[(wave * 32) * TBK];

  for (int k0 = 0; k0 < K; k0 += TBK) {
    gll16(Ag + k0, As0);
    gll16(Ag + k0 + 16 * K, As0 + 16 * TBK);
    gll16(Bg + k0, Bs0);
    gll16(Bg + k0 + 16 * K, Bs0 + 16 * TBK);
    asm volatile("s_waitcnt vmcnt(0)" ::: "memory");
    __syncthreads();

    bf16x8 af[4], bfr[4];
#pragma unroll
    for (int mt = 0; mt < 4; mt++)
      af[mt] = *(const bf16x8*)&As[(wm + mt * 16 + fr) * TBK + fq * 8];
#pragma unroll
    for (int nt = 0; nt < 4; nt++)
      bfr[nt] = *(const bf16x8*)&Bs[(wn + nt * 16 + fr) * TBK + fq * 8];
#pragma unroll
    for (int mt = 0; mt < 4; mt++)
#pragma unroll
      for (int nt = 0; nt < 4; nt++)
        acc[mt][nt] = __builtin_amdgcn_mfma_f32_16x16x32_bf16(af[mt], bfr[nt], acc[mt][nt], 0, 0, 0);
    __syncthreads();
  }

#pragma unroll
  for (int mt = 0; mt < 4; mt++)
#pragma unroll
    for (int nt = 0; nt < 4; nt++)
#pragma unroll
      for (int r = 0; r < 4; r++) {
        int row = bm + wm + mt * 16 + fq * 4 + r;
        int col = bn + wn + nt * 16 + fr;
        store_c(&C[(size_t)row * N + col], acc[mt][nt][r]);
      }
}

// ---------------------------------------------------------------------------
// Flash attention R7: transposed-MFMA, zero cross-lane P transfer.
//   S^T = mfma(A=K_frag, B=Q_frag): lane(q=fr,quad fq) holds
//         S[t = tt*16 + fq*4 + r][q] for tt=0..3.
//   PV k-order is CHOSEN so each lane's B-fragment slots are exactly the
//   t-values it already holds: chunk c, k=fq*8+j -> t = 32c+16(j>>2)+4fq+(j&3).
//   Vt is staged in the matching permuted slot order: slot(t)=32c+8fq+4jhi+r.
//   O^T = mfma(A=Vt_frag, B=P_frag); row sums via ones-A mfma.
// No Qs/Ps LDS; LDS = Ks+Vt = 18.4 KB -> 8 blocks/CU (grid fully resident).
// One block = 64 q-rows of one (b,h); wave w owns q rows w*16..w*16+15.
// ---------------------------------------------------------------------------
#define SQ 72  // LDS row stride: 16B-aligned, breaks pow2 banks

__global__ __launch_bounds__(256) void attn_kernel(
    const unsigned short* q, const unsigned short* k,
    const unsigned short* v, unsigned short* o) {
  const int S = 2048, E = 1024;
  __shared__ __attribute__((aligned(16))) unsigned short Ks[64 * SQ];
  __shared__ __attribute__((aligned(16))) unsigned short Vt[64 * SQ];  // [d][slot]

  const int tid = threadIdx.x;
  const int wave = tid >> 6, lane = tid & 63;
  const int fr = lane & 15, fq = lane >> 4;
  const int q0 = blockIdx.x * 64;
  const int bh = blockIdx.y;
  const int b = bh >> 4, h = bh & 15;
  const size_t base = ((size_t)b * S) * E + (size_t)h * 64;

  // Q B-fragments straight from global: lane holds Q[q0+wave*16+fr][ks*32+fq*8+j]
  bf16x8 aq[2];
#pragma unroll
  for (int ks = 0; ks < 2; ks++)
    aq[ks] = *(const bf16x8*)&q[base + (size_t)(q0 + wave * 16 + fr) * E + ks * 32 + fq * 8];

  // ones A-fragment for row-sum MFMA
  ushort8 ones_u;
#pragma unroll
  for (int j = 0; j < 8; j++) ones_u[j] = 0x3F80;  // bf16 1.0
  bf16x8 onesf = *(bf16x8*)&ones_u;

  f32x4 ot[4] = {};   // O^T tiles: d = dt*16 + fq*4 + r, q = fr
  f32x4 osum = {};    // every element = sum_t P[t][q=fr]
  const float KSC = 0.125f * 1.44269504088896341f;  // head_scale * log2(e)

  // V staging: thread handles t rows rp, rp+1 and d cols dcv..dcv+7,
  // written at permuted slot(t) (pairs stay adjacent: rp even -> r in {0,2}).
  const int rp = (tid & 31) * 2;
  const int dcv = (tid >> 5) * 8;
  const int u_ = rp & 31;
  const int slot = 32 * (rp >> 5) + 8 * ((u_ & 15) >> 2) + 4 * (u_ >> 4) + (u_ & 3);

  for (int t0 = 0; t0 < S; t0 += 64) {
    __syncthreads();
#pragma unroll
    for (int i = 0; i < 2; i++) {
      int id = tid + i * 256;
      int row = id >> 3, dc = (id & 7) * 8;
      ushort8 kv = *(const ushort8*)&k[base + (size_t)(t0 + row) * E + dc];
      *(ushort8*)&Ks[row * SQ + dc] = kv;
    }
    {
      ushort8 v0 = *(const ushort8*)&v[base + (size_t)(t0 + rp) * E + dcv];
      ushort8 v1 = *(const ushort8*)&v[base + (size_t)(t0 + rp + 1) * E + dcv];
#pragma unroll
      for (int j = 0; j < 8; j++) {
        uint32_t w = (uint32_t)v0[j] | ((uint32_t)v1[j] << 16);
        *(uint32_t*)&Vt[(dcv + j) * SQ + slot] = w;
      }
    }
    __syncthreads();

    // S^T tiles: st[tt][r] = score(q=fr, t = t0 + tt*16 + fq*4 + r)
    f32x4 st[4] = {};
#pragma unroll
    for (int ks = 0; ks < 2; ks++) {
#pragma unroll
      for (int tt = 0; tt < 4; tt++) {
        bf16x8 ak = *(const bf16x8*)&Ks[(tt * 16 + fr) * SQ + ks * 32 + fq * 8];
        st[tt] = __builtin_amdgcn_mfma_f32_16x16x32_bf16(ak, aq[ks], st[tt], 0, 0, 0);
      }
    }

    // exp; pack (r,r+1) bf16 pairs: pk[tt][w] = P at t = tt*16+fq*4+2w+{0,1}
    uint32_t pk[4][2];
#pragma unroll
    for (int tt = 0; tt < 4; tt++) {
      float e0 = __builtin_amdgcn_exp2f(st[tt][0] * KSC);
      float e1 = __builtin_amdgcn_exp2f(st[tt][1] * KSC);
      float e2 = __builtin_amdgcn_exp2f(st[tt][2] * KSC);
      float e3 = __builtin_amdgcn_exp2f(st[tt][3] * KSC);
      pk[tt][0] = pack_bf2(e0, e1);
      pk[tt][1] = pack_bf2(e2, e3);
    }

    // PV chunk c: B-fragment is a pure register repack (k-order matches the
    // t-values this lane holds); A reads Vt at the matching permuted slots.
#pragma unroll
    for (int c = 0; c < 2; c++) {
      u32x4 bpr;
      bpr[0] = pk[2 * c][0];
      bpr[1] = pk[2 * c][1];
      bpr[2] = pk[2 * c + 1][0];
      bpr[3] = pk[2 * c + 1][1];
      bf16x8 bp = *(bf16x8*)&bpr;
#pragma unroll
      for (int dt = 0; dt < 4; dt++) {
        bf16x8 av = *(const bf16x8*)&Vt[(dt * 16 + fr) * SQ + c * 32 + fq * 8];
        ot[dt] = __builtin_amdgcn_mfma_f32_16x16x32_bf16(av, bp, ot[dt], 0, 0, 0);
      }
      osum = __builtin_amdgcn_mfma_f32_16x16x32_bf16(onesf, bp, osum, 0, 0, 0);
    }
  }

  // write O[q][d]: q = q0 + wave*16 + fr, d = dt*16 + fq*4 + {0..3}
  {
    float inv = 1.0f / osum[0];
    size_t rowbase = base + (size_t)(q0 + wave * 16 + fr) * E;
#pragma unroll
    for (int dt = 0; dt < 4; dt++) {
      uint32_t w0 = pack_bf2(ot[dt][0] * inv, ot[dt][1] * inv);
      uint32_t w1 = pack_bf2(ot[dt][2] * inv, ot[dt][3] * inv);
      *(uint32_t*)&o[rowbase + dt * 16 + fq * 4] = w0;
      *(uint32_t*)&o[rowbase + dt * 16 + fq * 4 + 2] = w1;
    }
  }
}

// ---------------------------------------------------------------------------
// ws: 3 x 1M (weights) + 3 x 8M (q/k/v) shorts = 54 MB.
// bf16 hidden_states lives in d_out's first 16 MB (dead before final GEMM).
// woT reuses wqT's slot. Final GEMM writes fp32 to d_out.
// ---------------------------------------------------------------------------
extern "C" void kernel_launch(void* const* d_in, const int* in_sizes, int n_in,
                              void* d_out, int out_size, void* d_ws, size_t ws_size,
                              hipStream_t stream) {
  const float* hs = (const float*)d_in[0];
  const float* wq = (const float*)d_in[1];
  const float* wk = (const float*)d_in[2];
  const float* wv = (const float*)d_in[3];
  const float* wo = (const float*)d_in[4];
  unsigned short* ws = (unsigned short*)d_ws;

  unsigned short* wqT = ws;
  unsigned short* wkT = ws + 1048576;
  unsigned short* wvT = ws + 2097152;
  unsigned short* woT = wqT;
  unsigned short* qb  = ws + 3145728;
  unsigned short* kb  = qb + 8388608;
  unsigned short* vb  = kb + 8388608;
  unsigned short* ob  = qb;
  unsigned short* hsb = (unsigned short*)d_out;
  float* out = (float*)d_out;

  const int M = 8192, N = 1024, K = 1024;

  cvt_f32_bf16<<<dim3(M * K / 4 / 256), 256, 0, stream>>>(hs, hsb, M * K / 4);

  dim3 tb(32, 8);
  transpose_w<<<dim3(32, 32), tb, 0, stream>>>(wq, wqT);
  transpose_w<<<dim3(32, 32), tb, 0, stream>>>(wk, wkT);
  transpose_w<<<dim3(32, 32), tb, 0, stream>>>(wv, wvT);

  gemm_bt<unsigned short><<<dim3(M / 128, N / 128, 3), 256, 0, stream>>>(
      hsb, wqT, wkT, wvT, qb, kb, vb, M, N, K);

  transpose_w<<<dim3(32, 32), tb, 0, stream>>>(wo, woT);

  attn_kernel<<<dim3(2048 / 64, 64), 256, 0, stream>>>(qb, kb, vb, ob);

  gemm_bt<float><<<dim3(M / 128, N / 128, 1), 256, 0, stream>>>(
      ob, woT, woT, woT, out, out, out, M, N, K);
}

// Round 8
// 304.698 us; speedup vs baseline: 1.2544x; 1.0604x over previous
//
#include <hip/hip_runtime.h>
#include <stdint.h>

typedef __attribute__((ext_vector_type(8))) unsigned short ushort8;
typedef __attribute__((ext_vector_type(8))) __bf16 bf16x8;
typedef __attribute__((ext_vector_type(4))) float f32x4;
typedef __attribute__((ext_vector_type(4))) uint32_t u32x4;

#define TBK 32

__device__ __forceinline__ unsigned short f2bf(float f) {
  union { float f; uint32_t u; } x; x.f = f;
  uint32_t u = x.u;
  uint32_t r = (u + 0x7fffu + ((u >> 16) & 1u)) >> 16;
  return (unsigned short)r;
}

__device__ __forceinline__ uint32_t pack_bf2(float lo, float hi) {
  return (uint32_t)f2bf(lo) | ((uint32_t)f2bf(hi) << 16);
}

// round-half-up bf16 pair pack: 2 adds + 1 v_perm. For positive, non-tie
// values identical to RNE (half-ULP max error).
__device__ __forceinline__ uint32_t rhu2(float lo, float hi) {
  union { float f; uint32_t u; } a, b; a.f = lo; b.f = hi;
  return __builtin_amdgcn_perm(b.u + 0x8000u, a.u + 0x8000u, 0x07060302u);
}

__device__ __forceinline__ void store_c(unsigned short* p, float v) { *p = f2bf(v); }
__device__ __forceinline__ void store_c(float* p, float v) { *p = v; }

__device__ __forceinline__ void gll16(const unsigned short* g, unsigned short* l) {
  __builtin_amdgcn_global_load_lds((const __attribute__((address_space(1))) void*)g,
                                   (__attribute__((address_space(3))) void*)l,
                                   16, 0, 0);
}

// ---------------------------------------------------------------------------
// fp32 -> bf16 convert (RNE). One thread = 4 elements.
// ---------------------------------------------------------------------------
__global__ __launch_bounds__(256) void cvt_f32_bf16(
    const float* __restrict__ x, unsigned short* __restrict__ y, int n4) {
  int i = blockIdx.x * 256 + threadIdx.x;
  if (i >= n4) return;
  float4 v = *(const float4*)(x + (size_t)i * 4);
  uint2 p; p.x = pack_bf2(v.x, v.y); p.y = pack_bf2(v.z, v.w);
  *(uint2*)(y + (size_t)i * 4) = p;
}

// ---------------------------------------------------------------------------
// Weight transpose + convert: WT[n][k] = bf16(W[k][n]), 1024x1024 fp32 in.
// ---------------------------------------------------------------------------
__global__ void transpose_w(const float* __restrict__ W,
                            unsigned short* __restrict__ WT) {
  __shared__ unsigned short tile[32][33];
  int c0 = blockIdx.x * 32, r0 = blockIdx.y * 32;
  int x = threadIdx.x, y = threadIdx.y;
#pragma unroll
  for (int i = 0; i < 32; i += 8)
    tile[y + i][x] = f2bf(W[(size_t)(r0 + y + i) * 1024 + c0 + x]);
  __syncthreads();
#pragma unroll
  for (int i = 0; i < 32; i += 8)
    WT[(size_t)(c0 + y + i) * 1024 + r0 + x] = tile[x][y + i];
}

// ---------------------------------------------------------------------------
// GEMM: C[M,N] = A[M,K]*B[K,N] given BT[N,K], bf16 in, fp32 accum.
// m97 structure: 128x128 tile, 4 waves each 64x64, BK=32, global_load_lds.
// ---------------------------------------------------------------------------
template <typename OutT>
__global__ __launch_bounds__(256) void gemm_bt(
    const unsigned short* A,
    const unsigned short* BT0, const unsigned short* BT1, const unsigned short* BT2,
    OutT* C0, OutT* C1, OutT* C2,
    int M, int N, int K) {
  const unsigned short* BT = (blockIdx.z == 0) ? BT0 : (blockIdx.z == 1) ? BT1 : BT2;
  OutT* C = (blockIdx.z == 0) ? C0 : (blockIdx.z == 1) ? C1 : C2;

  __shared__ __attribute__((aligned(16))) unsigned short As[128 * TBK];
  __shared__ __attribute__((aligned(16))) unsigned short Bs[128 * TBK];

  const int tid = threadIdx.x;
  const int wave = tid >> 6, lane = tid & 63;
  const int fr = lane & 15, fq = lane >> 4;
  const int bm = blockIdx.x * 128, bn = blockIdx.y * 128;
  const int wm = (wave >> 1) * 64, wn = (wave & 1) * 64;

  f32x4 acc[4][4] = {};

  const int sr = lane >> 2;
  const int sk = (lane & 3) * 8;
  const unsigned short* Ag = A + (size_t)(bm + wave * 32 + sr) * K + sk;
  const unsigned short* Bg = BT + (size_t)(bn + wave * 32 + sr) * K + sk;
  unsigned short* As0 = &As[(wave * 32) * TBK];
  unsigned short* Bs0 = &Bs[(wave * 32) * TBK];

  for (int k0 = 0; k0 < K; k0 += TBK) {
    gll16(Ag + k0, As0);
    gll16(Ag + k0 + 16 * K, As0 + 16 * TBK);
    gll16(Bg + k0, Bs0);
    gll16(Bg + k0 + 16 * K, Bs0 + 16 * TBK);
    asm volatile("s_waitcnt vmcnt(0)" ::: "memory");
    __syncthreads();

    bf16x8 af[4], bfr[4];
#pragma unroll
    for (int mt = 0; mt < 4; mt++)
      af[mt] = *(const bf16x8*)&As[(wm + mt * 16 + fr) * TBK + fq * 8];
#pragma unroll
    for (int nt = 0; nt < 4; nt++)
      bfr[nt] = *(const bf16x8*)&Bs[(wn + nt * 16 + fr) * TBK + fq * 8];
#pragma unroll
    for (int mt = 0; mt < 4; mt++)
#pragma unroll
      for (int nt = 0; nt < 4; nt++)
        acc[mt][nt] = __builtin_amdgcn_mfma_f32_16x16x32_bf16(af[mt], bfr[nt], acc[mt][nt], 0, 0, 0);
    __syncthreads();
  }

#pragma unroll
  for (int mt = 0; mt < 4; mt++)
#pragma unroll
    for (int nt = 0; nt < 4; nt++)
#pragma unroll
      for (int r = 0; r < 4; r++) {
        int row = bm + wm + mt * 16 + fq * 4 + r;
        int col = bn + wn + nt * 16 + fr;
        store_c(&C[(size_t)row * N + col], acc[mt][nt][r]);
      }
}

// ---------------------------------------------------------------------------
// Flash attention R8: transposed-MFMA, zero cross-lane P transfer,
// v_perm-packed P and V (VALU diet vs R7).
//   S^T = mfma(A=K_frag, B=Q_frag): lane(q=fr,quad fq) holds
//         S[t = tt*16 + fq*4 + r][q], tt=0..3.
//   PV k-order chosen so each lane's B-fragment = its own P values:
//   chunk c, k=fq*8+j -> t = 32c+16(j>>2)+4fq+(j&3); Vt staged at
//   slot(t)=32c+8fq+4jhi+r. O^T = mfma(A=Vt_frag, B=P_frag).
// Row sums via ones-A mfma. LDS 18.4 KB.
// ---------------------------------------------------------------------------
#define SQ 72  // LDS row stride: 16B-aligned, breaks pow2 banks

__global__ __launch_bounds__(256) void attn_kernel(
    const unsigned short* q, const unsigned short* k,
    const unsigned short* v, unsigned short* o) {
  const int S = 2048, E = 1024;
  __shared__ __attribute__((aligned(16))) unsigned short Ks[64 * SQ];
  __shared__ __attribute__((aligned(16))) unsigned short Vt[64 * SQ];  // [d][slot]

  const int tid = threadIdx.x;
  const int wave = tid >> 6, lane = tid & 63;
  const int fr = lane & 15, fq = lane >> 4;
  const int q0 = blockIdx.x * 64;
  const int bh = blockIdx.y;
  const int b = bh >> 4, h = bh & 15;
  const size_t base = ((size_t)b * S) * E + (size_t)h * 64;

  bf16x8 aq[2];
#pragma unroll
  for (int ks = 0; ks < 2; ks++)
    aq[ks] = *(const bf16x8*)&q[base + (size_t)(q0 + wave * 16 + fr) * E + ks * 32 + fq * 8];

  ushort8 ones_u;
#pragma unroll
  for (int j = 0; j < 8; j++) ones_u[j] = 0x3F80;  // bf16 1.0
  bf16x8 onesf = *(bf16x8*)&ones_u;

  f32x4 ot[4] = {};
  f32x4 osum = {};
  const float KSC = 0.125f * 1.44269504088896341f;  // head_scale * log2(e)

  const int rp = (tid & 31) * 2;
  const int dcv = (tid >> 5) * 8;
  const int u_ = rp & 31;
  const int slot = 32 * (rp >> 5) + 8 * ((u_ & 15) >> 2) + 4 * (u_ >> 4) + (u_ & 3);

  for (int t0 = 0; t0 < S; t0 += 64) {
    __syncthreads();
#pragma unroll
    for (int i = 0; i < 2; i++) {
      int id = tid + i * 256;
      int row = id >> 3, dc = (id & 7) * 8;
      ushort8 kv = *(const ushort8*)&k[base + (size_t)(t0 + row) * E + dc];
      *(ushort8*)&Ks[row * SQ + dc] = kv;
    }
    {
      // V rows t0+rp (a) and t0+rp+1 (b) as u32x4; interleave 16-bit lanes
      // via v_perm: lo w -> {b.low16, a.low16}, hi w -> {b.hi16, a.hi16}.
      u32x4 a = *(const u32x4*)&v[base + (size_t)(t0 + rp) * E + dcv];
      u32x4 bb = *(const u32x4*)&v[base + (size_t)(t0 + rp + 1) * E + dcv];
#pragma unroll
      for (int w = 0; w < 4; w++) {
        uint32_t lo = __builtin_amdgcn_perm(bb[w], a[w], 0x05040100u);
        uint32_t hi = __builtin_amdgcn_perm(bb[w], a[w], 0x07060302u);
        *(uint32_t*)&Vt[(dcv + 2 * w) * SQ + slot] = lo;
        *(uint32_t*)&Vt[(dcv + 2 * w + 1) * SQ + slot] = hi;
      }
    }
    __syncthreads();

    // S^T tiles: st[tt][r] = score(q=fr, t = t0 + tt*16 + fq*4 + r)
    f32x4 st[4] = {};
#pragma unroll
    for (int ks = 0; ks < 2; ks++) {
#pragma unroll
      for (int tt = 0; tt < 4; tt++) {
        bf16x8 ak = *(const bf16x8*)&Ks[(tt * 16 + fr) * SQ + ks * 32 + fq * 8];
        st[tt] = __builtin_amdgcn_mfma_f32_16x16x32_bf16(ak, aq[ks], st[tt], 0, 0, 0);
      }
    }

    // exp2 then round-half-up pair pack (3 VALU/pair)
    uint32_t pk[4][2];
#pragma unroll
    for (int tt = 0; tt < 4; tt++) {
      float e0 = __builtin_amdgcn_exp2f(st[tt][0] * KSC);
      float e1 = __builtin_amdgcn_exp2f(st[tt][1] * KSC);
      float e2 = __builtin_amdgcn_exp2f(st[tt][2] * KSC);
      float e3 = __builtin_amdgcn_exp2f(st[tt][3] * KSC);
      pk[tt][0] = rhu2(e0, e1);
      pk[tt][1] = rhu2(e2, e3);
    }

#pragma unroll
    for (int c = 0; c < 2; c++) {
      u32x4 bpr;
      bpr[0] = pk[2 * c][0];
      bpr[1] = pk[2 * c][1];
      bpr[2] = pk[2 * c + 1][0];
      bpr[3] = pk[2 * c + 1][1];
      bf16x8 bp = *(bf16x8*)&bpr;
#pragma unroll
      for (int dt = 0; dt < 4; dt++) {
        bf16x8 av = *(const bf16x8*)&Vt[(dt * 16 + fr) * SQ + c * 32 + fq * 8];
        ot[dt] = __builtin_amdgcn_mfma_f32_16x16x32_bf16(av, bp, ot[dt], 0, 0, 0);
      }
      osum = __builtin_amdgcn_mfma_f32_16x16x32_bf16(onesf, bp, osum, 0, 0, 0);
    }
  }

  // write O[q][d]: q = q0 + wave*16 + fr, d = dt*16 + fq*4 + {0..3}
  {
    float inv = 1.0f / osum[0];
    size_t rowbase = base + (size_t)(q0 + wave * 16 + fr) * E;
#pragma unroll
    for (int dt = 0; dt < 4; dt++) {
      uint32_t w0 = rhu2(ot[dt][0] * inv, ot[dt][1] * inv);
      uint32_t w1 = rhu2(ot[dt][2] * inv, ot[dt][3] * inv);
      *(uint32_t*)&o[rowbase + dt * 16 + fq * 4] = w0;
      *(uint32_t*)&o[rowbase + dt * 16 + fq * 4 + 2] = w1;
    }
  }
}

// ---------------------------------------------------------------------------
// ws: 3 x 1M (weights) + 3 x 8M (q/k/v) shorts = 54 MB.
// bf16 hidden_states lives in d_out's first 16 MB (dead before final GEMM).
// woT reuses wqT's slot. Final GEMM writes fp32 to d_out.
// ---------------------------------------------------------------------------
extern "C" void kernel_launch(void* const* d_in, const int* in_sizes, int n_in,
                              void* d_out, int out_size, void* d_ws, size_t ws_size,
                              hipStream_t stream) {
  const float* hs = (const float*)d_in[0];
  const float* wq = (const float*)d_in[1];
  const float* wk = (const float*)d_in[2];
  const float* wv = (const float*)d_in[3];
  const float* wo = (const float*)d_in[4];
  unsigned short* ws = (unsigned short*)d_ws;

  unsigned short* wqT = ws;
  unsigned short* wkT = ws + 1048576;
  unsigned short* wvT = ws + 2097152;
  unsigned short* woT = wqT;
  unsigned short* qb  = ws + 3145728;
  unsigned short* kb  = qb + 8388608;
  unsigned short* vb  = kb + 8388608;
  unsigned short* ob  = qb;
  unsigned short* hsb = (unsigned short*)d_out;
  float* out = (float*)d_out;

  const int M = 8192, N = 1024, K = 1024;

  cvt_f32_bf16<<<dim3(M * K / 4 / 256), 256, 0, stream>>>(hs, hsb, M * K / 4);

  dim3 tb(32, 8);
  transpose_w<<<dim3(32, 32), tb, 0, stream>>>(wq, wqT);
  transpose_w<<<dim3(32, 32), tb, 0, stream>>>(wk, wkT);
  transpose_w<<<dim3(32, 32), tb, 0, stream>>>(wv, wvT);

  gemm_bt<unsigned short><<<dim3(M / 128, N / 128, 3), 256, 0, stream>>>(
      hsb, wqT, wkT, wvT, qb, kb, vb, M, N, K);

  transpose_w<<<dim3(32, 32), tb, 0, stream>>>(wo, woT);

  attn_kernel<<<dim3(2048 / 64, 64), 256, 0, stream>>>(qb, kb, vb, ob);

  gemm_bt<float><<<dim3(M / 128, N / 128, 1), 256, 0, stream>>>(
      ob, woT, woT, woT, out, out, out, M, N, K);
}

// Round 9
// 289.617 us; speedup vs baseline: 1.3197x; 1.0521x over previous
//
#include <hip/hip_runtime.h>
#include <stdint.h>

typedef __attribute__((ext_vector_type(8))) unsigned short ushort8;
typedef __attribute__((ext_vector_type(8))) __bf16 bf16x8;
typedef __attribute__((ext_vector_type(4))) float f32x4;
typedef __attribute__((ext_vector_type(4))) uint32_t u32x4;

#define TBK 32

__device__ __forceinline__ unsigned short f2bf(float f) {
  union { float f; uint32_t u; } x; x.f = f;
  uint32_t u = x.u;
  uint32_t r = (u + 0x7fffu + ((u >> 16) & 1u)) >> 16;
  return (unsigned short)r;
}

__device__ __forceinline__ uint32_t pack_bf2(float lo, float hi) {
  return (uint32_t)f2bf(lo) | ((uint32_t)f2bf(hi) << 16);
}

// round-half-up bf16 pair pack: 2 adds + 1 v_perm (≡ RNE for positive non-ties)
__device__ __forceinline__ uint32_t rhu2(float lo, float hi) {
  union { float f; uint32_t u; } a, b; a.f = lo; b.f = hi;
  return __builtin_amdgcn_perm(b.u + 0x8000u, a.u + 0x8000u, 0x07060302u);
}

__device__ __forceinline__ void store_c(unsigned short* p, float v) { *p = f2bf(v); }
__device__ __forceinline__ void store_c(float* p, float v) { *p = v; }

__device__ __forceinline__ void gll16(const unsigned short* g, unsigned short* l) {
  __builtin_amdgcn_global_load_lds((const __attribute__((address_space(1))) void*)g,
                                   (__attribute__((address_space(3))) void*)l,
                                   16, 0, 0);
}

// ---------------------------------------------------------------------------
// fp32 -> bf16 convert (RNE). One thread = 4 elements.
// ---------------------------------------------------------------------------
__global__ __launch_bounds__(256) void cvt_f32_bf16(
    const float* __restrict__ x, unsigned short* __restrict__ y, int n4) {
  int i = blockIdx.x * 256 + threadIdx.x;
  if (i >= n4) return;
  float4 v = *(const float4*)(x + (size_t)i * 4);
  uint2 p; p.x = pack_bf2(v.x, v.y); p.y = pack_bf2(v.z, v.w);
  *(uint2*)(y + (size_t)i * 4) = p;
}

// ---------------------------------------------------------------------------
// Weight transpose + convert: WT[n][k] = bf16(W[k][n]), 1024x1024 fp32 in.
// ---------------------------------------------------------------------------
__global__ void transpose_w(const float* __restrict__ W,
                            unsigned short* __restrict__ WT) {
  __shared__ unsigned short tile[32][33];
  int c0 = blockIdx.x * 32, r0 = blockIdx.y * 32;
  int x = threadIdx.x, y = threadIdx.y;
#pragma unroll
  for (int i = 0; i < 32; i += 8)
    tile[y + i][x] = f2bf(W[(size_t)(r0 + y + i) * 1024 + c0 + x]);
  __syncthreads();
#pragma unroll
  for (int i = 0; i < 32; i += 8)
    WT[(size_t)(c0 + y + i) * 1024 + r0 + x] = tile[x][y + i];
}

// ---------------------------------------------------------------------------
// GEMM: C[M,N] = A[M,K]*B[K,N] given BT[N,K], bf16 in, fp32 accum.
// m97 structure: 128x128 tile, 4 waves each 64x64, BK=32, global_load_lds.
// ---------------------------------------------------------------------------
template <typename OutT>
__global__ __launch_bounds__(256) void gemm_bt(
    const unsigned short* A,
    const unsigned short* BT0, const unsigned short* BT1, const unsigned short* BT2,
    OutT* C0, OutT* C1, OutT* C2,
    int M, int N, int K) {
  const unsigned short* BT = (blockIdx.z == 0) ? BT0 : (blockIdx.z == 1) ? BT1 : BT2;
  OutT* C = (blockIdx.z == 0) ? C0 : (blockIdx.z == 1) ? C1 : C2;

  __shared__ __attribute__((aligned(16))) unsigned short As[128 * TBK];
  __shared__ __attribute__((aligned(16))) unsigned short Bs[128 * TBK];

  const int tid = threadIdx.x;
  const int wave = tid >> 6, lane = tid & 63;
  const int fr = lane & 15, fq = lane >> 4;
  const int bm = blockIdx.x * 128, bn = blockIdx.y * 128;
  const int wm = (wave >> 1) * 64, wn = (wave & 1) * 64;

  f32x4 acc[4][4] = {};

  const int sr = lane >> 2;
  const int sk = (lane & 3) * 8;
  const unsigned short* Ag = A + (size_t)(bm + wave * 32 + sr) * K + sk;
  const unsigned short* Bg = BT + (size_t)(bn + wave * 32 + sr) * K + sk;
  unsigned short* As0 = &As[(wave * 32) * TBK];
  unsigned short* Bs0 = &Bs[(wave * 32) * TBK];

  for (int k0 = 0; k0 < K; k0 += TBK) {
    gll16(Ag + k0, As0);
    gll16(Ag + k0 + 16 * K, As0 + 16 * TBK);
    gll16(Bg + k0, Bs0);
    gll16(Bg + k0 + 16 * K, Bs0 + 16 * TBK);
    asm volatile("s_waitcnt vmcnt(0)" ::: "memory");
    __syncthreads();

    bf16x8 af[4], bfr[4];
#pragma unroll
    for (int mt = 0; mt < 4; mt++)
      af[mt] = *(const bf16x8*)&As[(wm + mt * 16 + fr) * TBK + fq * 8];
#pragma unroll
    for (int nt = 0; nt < 4; nt++)
      bfr[nt] = *(const bf16x8*)&Bs[(wn + nt * 16 + fr) * TBK + fq * 8];
#pragma unroll
    for (int mt = 0; mt < 4; mt++)
#pragma unroll
      for (int nt = 0; nt < 4; nt++)
        acc[mt][nt] = __builtin_amdgcn_mfma_f32_16x16x32_bf16(af[mt], bfr[nt], acc[mt][nt], 0, 0, 0);
    __syncthreads();
  }

#pragma unroll
  for (int mt = 0; mt < 4; mt++)
#pragma unroll
    for (int nt = 0; nt < 4; nt++)
#pragma unroll
      for (int r = 0; r < 4; r++) {
        int row = bm + wm + mt * 16 + fq * 4 + r;
        int col = bn + wn + nt * 16 + fr;
        store_c(&C[(size_t)row * N + col], acc[mt][nt][r]);
      }
}

// ---------------------------------------------------------------------------
// Flash attention R9: transposed-MFMA, zero cross-lane P transfer, and
// 32 q-rows per wave (qg=0,1) so every Ks/Vt LDS read feeds TWO MFMAs —
// halves the (dominant) per-CU LDS read traffic per unit work.
//   S^T = mfma(A=K_frag, B=Q_frag); PV k-order: chunk c, k=fq*8+j ->
//   t = 32c+16(j>>2)+4fq+(j&3); Vt staged at slot(t)=32c+8fq+4jhi+r.
// Row sums via ones-A mfma. One block = 128 q-rows of one (b,h).
// LDS 18.4 KB; grid (16, 64) = 1024 blocks = 4 blocks/CU.
// ---------------------------------------------------------------------------
#define SQ 72  // LDS row stride: 16B-aligned, breaks pow2 banks

__global__ __launch_bounds__(256, 4) void attn_kernel(
    const unsigned short* q, const unsigned short* k,
    const unsigned short* v, unsigned short* o) {
  const int S = 2048, E = 1024;
  __shared__ __attribute__((aligned(16))) unsigned short Ks[64 * SQ];
  __shared__ __attribute__((aligned(16))) unsigned short Vt[64 * SQ];  // [d][slot]

  const int tid = threadIdx.x;
  const int wave = tid >> 6, lane = tid & 63;
  const int fr = lane & 15, fq = lane >> 4;
  const int q0 = blockIdx.x * 128;
  const int bh = blockIdx.y;
  const int b = bh >> 4, h = bh & 15;
  const size_t base = ((size_t)b * S) * E + (size_t)h * 64;

  // Q B-fragments for both q-groups (rows q0 + qg*64 + wave*16 + fr)
  bf16x8 aq[2][2];
#pragma unroll
  for (int qg = 0; qg < 2; qg++)
#pragma unroll
    for (int ks = 0; ks < 2; ks++)
      aq[qg][ks] = *(const bf16x8*)&q[base +
          (size_t)(q0 + qg * 64 + wave * 16 + fr) * E + ks * 32 + fq * 8];

  ushort8 ones_u;
#pragma unroll
  for (int j = 0; j < 8; j++) ones_u[j] = 0x3F80;  // bf16 1.0
  bf16x8 onesf = *(bf16x8*)&ones_u;

  f32x4 ot[2][4] = {};
  f32x4 osum[2] = {};
  const float KSC = 0.125f * 1.44269504088896341f;  // head_scale * log2(e)

  const int rp = (tid & 31) * 2;
  const int dcv = (tid >> 5) * 8;
  const int u_ = rp & 31;
  const int slot = 32 * (rp >> 5) + 8 * ((u_ & 15) >> 2) + 4 * (u_ >> 4) + (u_ & 3);

  for (int t0 = 0; t0 < S; t0 += 64) {
    __syncthreads();
#pragma unroll
    for (int i = 0; i < 2; i++) {
      int id = tid + i * 256;
      int row = id >> 3, dc = (id & 7) * 8;
      ushort8 kv = *(const ushort8*)&k[base + (size_t)(t0 + row) * E + dc];
      *(ushort8*)&Ks[row * SQ + dc] = kv;
    }
    {
      u32x4 a = *(const u32x4*)&v[base + (size_t)(t0 + rp) * E + dcv];
      u32x4 bb = *(const u32x4*)&v[base + (size_t)(t0 + rp + 1) * E + dcv];
#pragma unroll
      for (int w = 0; w < 4; w++) {
        uint32_t lo = __builtin_amdgcn_perm(bb[w], a[w], 0x05040100u);
        uint32_t hi = __builtin_amdgcn_perm(bb[w], a[w], 0x07060302u);
        *(uint32_t*)&Vt[(dcv + 2 * w) * SQ + slot] = lo;
        *(uint32_t*)&Vt[(dcv + 2 * w + 1) * SQ + slot] = hi;
      }
    }
    __syncthreads();

    // S^T: each ak read feeds both q-groups
    f32x4 st[2][4] = {};
#pragma unroll
    for (int ks = 0; ks < 2; ks++) {
#pragma unroll
      for (int tt = 0; tt < 4; tt++) {
        bf16x8 ak = *(const bf16x8*)&Ks[(tt * 16 + fr) * SQ + ks * 32 + fq * 8];
        st[0][tt] = __builtin_amdgcn_mfma_f32_16x16x32_bf16(ak, aq[0][ks], st[0][tt], 0, 0, 0);
        st[1][tt] = __builtin_amdgcn_mfma_f32_16x16x32_bf16(ak, aq[1][ks], st[1][tt], 0, 0, 0);
      }
    }

    // exp2 + round-half-up pair pack, per q-group
    uint32_t pk[2][4][2];
#pragma unroll
    for (int qg = 0; qg < 2; qg++)
#pragma unroll
      for (int tt = 0; tt < 4; tt++) {
        float e0 = __builtin_amdgcn_exp2f(st[qg][tt][0] * KSC);
        float e1 = __builtin_amdgcn_exp2f(st[qg][tt][1] * KSC);
        float e2 = __builtin_amdgcn_exp2f(st[qg][tt][2] * KSC);
        float e3 = __builtin_amdgcn_exp2f(st[qg][tt][3] * KSC);
        pk[qg][tt][0] = rhu2(e0, e1);
        pk[qg][tt][1] = rhu2(e2, e3);
      }

    // PV: each av read feeds both q-groups
#pragma unroll
    for (int c = 0; c < 2; c++) {
      bf16x8 bp[2];
#pragma unroll
      for (int qg = 0; qg < 2; qg++) {
        u32x4 bpr;
        bpr[0] = pk[qg][2 * c][0];
        bpr[1] = pk[qg][2 * c][1];
        bpr[2] = pk[qg][2 * c + 1][0];
        bpr[3] = pk[qg][2 * c + 1][1];
        bp[qg] = *(bf16x8*)&bpr;
      }
#pragma unroll
      for (int dt = 0; dt < 4; dt++) {
        bf16x8 av = *(const bf16x8*)&Vt[(dt * 16 + fr) * SQ + c * 32 + fq * 8];
        ot[0][dt] = __builtin_amdgcn_mfma_f32_16x16x32_bf16(av, bp[0], ot[0][dt], 0, 0, 0);
        ot[1][dt] = __builtin_amdgcn_mfma_f32_16x16x32_bf16(av, bp[1], ot[1][dt], 0, 0, 0);
      }
      osum[0] = __builtin_amdgcn_mfma_f32_16x16x32_bf16(onesf, bp[0], osum[0], 0, 0, 0);
      osum[1] = __builtin_amdgcn_mfma_f32_16x16x32_bf16(onesf, bp[1], osum[1], 0, 0, 0);
    }
  }

  // write O[q][d]: q = q0 + qg*64 + wave*16 + fr, d = dt*16 + fq*4 + {0..3}
#pragma unroll
  for (int qg = 0; qg < 2; qg++) {
    float inv = 1.0f / osum[qg][0];
    size_t rowbase = base + (size_t)(q0 + qg * 64 + wave * 16 + fr) * E;
#pragma unroll
    for (int dt = 0; dt < 4; dt++) {
      uint32_t w0 = rhu2(ot[qg][dt][0] * inv, ot[qg][dt][1] * inv);
      uint32_t w1 = rhu2(ot[qg][dt][2] * inv, ot[qg][dt][3] * inv);
      *(uint32_t*)&o[rowbase + dt * 16 + fq * 4] = w0;
      *(uint32_t*)&o[rowbase + dt * 16 + fq * 4 + 2] = w1;
    }
  }
}

// ---------------------------------------------------------------------------
// ws: 3 x 1M (weights) + 3 x 8M (q/k/v) shorts = 54 MB.
// bf16 hidden_states lives in d_out's first 16 MB (dead before final GEMM).
// woT reuses wqT's slot. Final GEMM writes fp32 to d_out.
// ---------------------------------------------------------------------------
extern "C" void kernel_launch(void* const* d_in, const int* in_sizes, int n_in,
                              void* d_out, int out_size, void* d_ws, size_t ws_size,
                              hipStream_t stream) {
  const float* hs = (const float*)d_in[0];
  const float* wq = (const float*)d_in[1];
  const float* wk = (const float*)d_in[2];
  const float* wv = (const float*)d_in[3];
  const float* wo = (const float*)d_in[4];
  unsigned short* ws = (unsigned short*)d_ws;

  unsigned short* wqT = ws;
  unsigned short* wkT = ws + 1048576;
  unsigned short* wvT = ws + 2097152;
  unsigned short* woT = wqT;
  unsigned short* qb  = ws + 3145728;
  unsigned short* kb  = qb + 8388608;
  unsigned short* vb  = kb + 8388608;
  unsigned short* ob  = qb;
  unsigned short* hsb = (unsigned short*)d_out;
  float* out = (float*)d_out;

  const int M = 8192, N = 1024, K = 1024;

  cvt_f32_bf16<<<dim3(M * K / 4 / 256), 256, 0, stream>>>(hs, hsb, M * K / 4);

  dim3 tb(32, 8);
  transpose_w<<<dim3(32, 32), tb, 0, stream>>>(wq, wqT);
  transpose_w<<<dim3(32, 32), tb, 0, stream>>>(wk, wkT);
  transpose_w<<<dim3(32, 32), tb, 0, stream>>>(wv, wvT);

  gemm_bt<unsigned short><<<dim3(M / 128, N / 128, 3), 256, 0, stream>>>(
      hsb, wqT, wkT, wvT, qb, kb, vb, M, N, K);

  transpose_w<<<dim3(32, 32), tb, 0, stream>>>(wo, woT);

  attn_kernel<<<dim3(2048 / 128, 64), 256, 0, stream>>>(qb, kb, vb, ob);

  gemm_bt<float><<<dim3(M / 128, N / 128, 1), 256, 0, stream>>>(
      ob, woT, woT, woT, out, out, out, M, N, K);
}